// Round 4
// baseline (277.862 us; speedup 1.0000x reference)
//
#include <hip/hip_runtime.h>
#include <hip/hip_cooperative_groups.h>

namespace cg = cooperative_groups;

typedef unsigned char u8;
typedef float f32x4 __attribute__((ext_vector_type(4)));
typedef _Float16 f16x8 __attribute__((ext_vector_type(8)));

#define DIM 128
#define TM  128

__device__ __forceinline__ float fast_tanh(float x) {
    // tanh(x) = 1 - 2/(exp2(2x*log2e)+1); exact +-1 saturation via inf->0
    float e = __builtin_amdgcn_exp2f(x * 2.885390081777927f);
    return 1.0f - 2.0f * __builtin_amdgcn_rcpf(e + 1.0f);
}
__device__ __forceinline__ float fast_sigmoid(float x) {
    float e = __builtin_amdgcn_exp2f(x * -1.4426950408889634f);
    return __builtin_amdgcn_rcpf(1.0f + e);
}

// ---- prep: W2T[n][k] = fp16(W2[k][n]) ----
__global__ __launch_bounds__(256) void prep_w2t(const float* __restrict__ W2,
                                                _Float16* __restrict__ W2T) {
    int idx = blockIdx.x * 256 + threadIdx.x;   // 0..16383
    int n = idx >> 7, k = idx & 127;
    W2T[n * DIM + k] = (_Float16)W2[k * DIM + n];
}

// ---- fused MLP eval, ALL 5 resolutions, zero LDS, fp16 MFMA ----
// 8 waves/block, each wave: 16 points x 128 out-dims. Lane computes exactly
// its own MFMA A-fragment (row=lane&15, k=(lane>>4)*8..+8) -> no LDS, no barrier.
// blocks: [0,9) R33 | [9,43) R65 | [43,174) R129 | [174,691) R257 | [691,2748) R513
__global__ __launch_bounds__(512, 4) void eval_all_mfma(
    const float* __restrict__ W1, const float* __restrict__ b1,
    const _Float16* __restrict__ W2T, const float* __restrict__ b2,
    const float* __restrict__ W3, const float* __restrict__ b3,
    const float* __restrict__ bmin, const float* __restrict__ bmax,
    float* __restrict__ q0, float* __restrict__ q1, float* __restrict__ q2,
    float* __restrict__ q3, float* __restrict__ q4)
{
    const int tid = threadIdx.x;
    const int bid = blockIdx.x;
    int R, m0; float* out;
    if      (bid < 9)   { R = 33;  out = q0; m0 = bid * TM; }
    else if (bid < 43)  { R = 65;  out = q1; m0 = (bid - 9) * TM; }
    else if (bid < 174) { R = 129; out = q2; m0 = (bid - 43) * TM; }
    else if (bid < 691) { R = 257; out = q3; m0 = (bid - 174) * TM; }
    else                { R = 513; out = q4; m0 = (bid - 691) * TM; }
    const int N = R * R;

    const int w = tid >> 6, lane = tid & 63;
    const int l15 = lane & 15, lg = lane >> 4;

    // this lane's point for layer-1 (A-fragment row = l15)
    const int pi = m0 + w * 16 + l15;
    const int pg = (pi < N) ? pi : N - 1;
    const int gi = pg / R, gj = pg - gi * R;
    const float inv = 1.0f / (float)(R - 1);    // R-1 pow2 -> exact
    const float x = bmin[0] + (float)gj * inv * (bmax[0] - bmin[0]);
    const float y = bmin[1] + (float)gi * inv * (bmax[1] - bmin[1]);

    f32x4 acc[8];
    #pragma unroll
    for (int nf = 0; nf < 8; ++nf) acc[nf] = (f32x4)(0.0f);

    #pragma unroll
    for (int kf = 0; kf < 4; ++kf) {
        const int kbase = kf * 32 + lg * 8;     // this lane's k-octet
        // layer-1: h1 = tanh(x*W1x + y*W1y + b1) for 8 dims, straight to fp16
        f32x4 wxa = *(const f32x4*)&W1[kbase];
        f32x4 wxb = *(const f32x4*)&W1[kbase + 4];
        f32x4 wya = *(const f32x4*)&W1[DIM + kbase];
        f32x4 wyb = *(const f32x4*)&W1[DIM + kbase + 4];
        f32x4 b1a = *(const f32x4*)&b1[kbase];
        f32x4 b1b = *(const f32x4*)&b1[kbase + 4];
        f16x8 ah;
        #pragma unroll
        for (int qq = 0; qq < 4; ++qq)
            ah[qq] = (_Float16)fast_tanh(fmaf(x, wxa[qq], fmaf(y, wya[qq], b1a[qq])));
        #pragma unroll
        for (int qq = 0; qq < 4; ++qq)
            ah[4 + qq] = (_Float16)fast_tanh(fmaf(x, wxb[qq], fmaf(y, wyb[qq], b1b[qq])));
        // B fragments straight from global (L1/L2-resident 32KB)
        #pragma unroll
        for (int nf = 0; nf < 8; ++nf) {
            int c = nf * 16 + l15;              // B col = lane&15
            f16x8 bh = *(const f16x8*)&W2T[c * DIM + kbase];
            acc[nf] = __builtin_amdgcn_mfma_f32_16x16x32_f16(ah, bh, acc[nf], 0, 0, 0);
        }
    }

    // ---- epilogue in registers ----
    // C/D: row(point) = w*16 + lg*4 + rg, col = nf*16 + l15
    float rs[4] = {0.0f, 0.0f, 0.0f, 0.0f};
    #pragma unroll
    for (int nf = 0; nf < 8; ++nf) {
        int c = nf * 16 + l15;
        float w3v = W3[c], b2v = b2[c];
        #pragma unroll
        for (int rg = 0; rg < 4; ++rg)
            rs[rg] += fast_tanh(acc[nf][rg] + b2v) * w3v;
    }
    #pragma unroll
    for (int rg = 0; rg < 4; ++rg) {
        float v = rs[rg];
        v += __shfl_xor(v, 1);
        v += __shfl_xor(v, 2);
        v += __shfl_xor(v, 4);
        v += __shfl_xor(v, 8);
        rs[rg] = v;
    }
    if (l15 == 0) {
        float b3v = b3[0];
        #pragma unroll
        for (int rg = 0; rg < 4; ++rg) {
            int po = m0 + w * 16 + lg * 4 + rg;
            if (po < N) out[po] = fast_sigmoid(rs[rg] + b3v);
        }
    }
}

// ---- all 4 refinement levels in ONE cooperative launch ----
#define TS 32
#define HW 40   // TS + 2*4 halo
struct LevelCfg { const float* occP; const u8* calcP; const float* q;
                  float* occO; u8* calcO; int Rp, R, nT; };

__device__ void process_tile(const LevelCfg& L, int t,
                             float* sOcc, float* sQ, u8* sRaw, u8* sCalc,
                             u8* sCfA, u8* sCfB)
{
    const int nT = L.nT, R = L.R, Rp = L.Rp;
    const int bi = t / nT, bj = t - bi * nT;
    const int fi0 = bi * TS - 4, fj0 = bj * TS - 4;
    const int tid = threadIdx.x;
    const float BAL = 0.5f;

    // phase 1: occ-interp + raw + c0 + q for the 40x40 region
    for (int c = tid; c < HW * HW; c += 256) {
        int li = c / HW, lj = c - li * HW;
        int fi = fi0 + li, fj = fj0 + lj;
        float occi = 0.5f, qv = 0.5f; u8 rw = 0, cal = 0;
        if (fi >= 0 && fi < R && fj >= 0 && fj < R) {
            int ip = fi >> 1, jp = fj >> 1;
            float tl = L.occP[ip * Rp + jp];
            int oi = fi & 1, oj = fj & 1;
            bool b;
            if (!oi && !oj) { occi = tl; b = false; }
            else if (oi && !oj) {
                float bl = L.occP[(ip + 1) * Rp + jp];
                occi = 0.5f * (tl + bl);
                b = (tl > BAL) != (bl > BAL);
            } else if (!oi && oj) {
                float tr = L.occP[ip * Rp + jp + 1];
                occi = 0.5f * (tl + tr);
                b = (tl > BAL) != (tr > BAL);
            } else {
                float bl = L.occP[(ip + 1) * Rp + jp];
                float tr = L.occP[ip * Rp + jp + 1];
                float br = L.occP[(ip + 1) * Rp + jp + 1];
                occi = 0.5f * (0.5f * (tl + bl) + 0.5f * (tr + br)); // exact _up2 order
                bool m0 = tl > BAL, m1 = bl > BAL, m2 = tr > BAL, m3 = br > BAL;
                b = (m0 | m1 | m2 | m3) && !(m0 & m1 & m2 & m3);
            }
            rw = b ? 1 : 0;
            if (((fi | fj) & 1) == 0) cal = L.calcP ? L.calcP[ip * Rp + jp] : 1;
            qv = L.q[fi * R + fj];
        }
        sOcc[c] = occi; sQ[c] = qv; sRaw[c] = rw; sCalc[c] = cal;
        sCfA[c] = 0; sCfB[c] = 0;
    }
    __syncthreads();

    // phase 2: boundary = any3x3(raw) & ~c0; conflicts0; occ select
    for (int c = tid; c < HW * HW; c += 256) {
        int li = c / HW, lj = c - li * HW;
        if (li < 1 || li >= HW - 1 || lj < 1 || lj >= HW - 1) continue;
        int fi = fi0 + li, fj = fj0 + lj;
        if (fi < 0 || fi >= R || fj < 0 || fj >= R) continue;
        bool b = false;
        #pragma unroll
        for (int di = -1; di <= 1; ++di)
            #pragma unroll
            for (int dj = -1; dj <= 1; ++dj)
                if (sRaw[(li + di) * HW + (lj + dj)]) b = true;
        b = b && !sCalc[c];
        float oi = sOcc[c], qq = sQ[c];
        u8 cf = (b && (oi - BAL) * (qq - BAL) < 0.0f) ? 1 : 0;
        if (b) { sOcc[c] = qq; sCalc[c] = 1; }
        sCfA[c] = cf;
    }
    __syncthreads();

    // 3 conflict-propagation iterations
    for (int it = 0; it < 3; ++it) {
        const u8* cin = (it & 1) ? sCfB : sCfA;
        u8* cout      = (it & 1) ? sCfA : sCfB;
        int lo = 2 + it, hi = HW - 2 - it;
        for (int c = tid; c < HW * HW; c += 256) {
            int li = c / HW, lj = c - li * HW;
            if (li < lo || li >= hi || lj < lo || lj >= hi) continue;
            int fi = fi0 + li, fj = fj0 + lj;
            if (fi < 0 || fi >= R || fj < 0 || fj >= R) continue;
            bool any = false;
            #pragma unroll
            for (int di = -1; di <= 1; ++di)
                #pragma unroll
                for (int dj = -1; dj <= 1; ++dj)
                    if (cin[(li + di) * HW + (lj + dj)]) any = true;
            bool cand = any && !sCalc[c];
            float oc = sOcc[c], qq = sQ[c];
            u8 nc = (cand && (oc - BAL) * (qq - BAL) < 0.0f) ? 1 : 0;
            if (cand) { sOcc[c] = qq; sCalc[c] = 1; }
            cout[c] = nc;
        }
        __syncthreads();
    }

    // write core 32x32
    for (int c = tid; c < HW * HW; c += 256) {
        int li = c / HW, lj = c - li * HW;
        if (li < 4 || li >= HW - 4 || lj < 4 || lj >= HW - 4) continue;
        int fi = fi0 + li, fj = fj0 + lj;
        if (fi < 0 || fi >= R || fj < 0 || fj >= R) continue;
        L.occO[fi * R + fj] = sOcc[c];
        L.calcO[fi * R + fj] = sCalc[c];
    }
    __syncthreads();   // LDS reused by next tile / next level
}

__global__ __launch_bounds__(256) void levels_coop(
    const float* q0, const float* q1, const float* q2, const float* q3,
    const float* q4, float* occA, float* occB, u8* calcA, u8* calcB,
    float* out)
{
    __shared__ float sOcc[HW * HW], sQ[HW * HW];
    __shared__ u8 sRaw[HW * HW], sCalc[HW * HW], sCfA[HW * HW], sCfB[HW * HW];
    cg::grid_group grid = cg::this_grid();

    LevelCfg cfg[4] = {
        { q0,   nullptr, q1, occA, calcB, 33,  65,  3  },
        { occA, calcB,   q2, occB, calcA, 65,  129, 5  },
        { occB, calcA,   q3, occA, calcB, 129, 257, 9  },
        { occA, calcB,   q4, out,  calcA, 257, 513, 17 },
    };
    for (int l = 0; l < 4; ++l) {
        const LevelCfg& L = cfg[l];
        for (int t = blockIdx.x; t < L.nT * L.nT; t += gridDim.x)
            process_tile(L, t, sOcc, sQ, sRaw, sCalc, sCfA, sCfB);
        if (l < 3) grid.sync();
    }
}

extern "C" void kernel_launch(void* const* d_in, const int* in_sizes, int n_in,
                              void* d_out, int out_size, void* d_ws, size_t ws_size,
                              hipStream_t stream) {
    const float* W1   = (const float*)d_in[0];
    const float* b1   = (const float*)d_in[1];
    const float* W2   = (const float*)d_in[2];
    const float* b2   = (const float*)d_in[3];
    const float* W3   = (const float*)d_in[4];
    const float* b3   = (const float*)d_in[5];
    const float* bmin = (const float*)d_in[6];
    const float* bmax = (const float*)d_in[7];

    const int N33 = 33 * 33, N65 = 65 * 65, N129 = 129 * 129,
              N257 = 257 * 257, N513 = 513 * 513;

    _Float16* W2T = (_Float16*)d_ws;                   // 32 KB, 16B-aligned
    float* q0 = (float*)((char*)d_ws + 32768);
    float* q1 = q0 + N33;
    float* q2 = q1 + N65;
    float* q3 = q2 + N129;
    float* q4 = q3 + N257;
    float* occA = q4 + N513;
    float* occB = occA + N513;
    u8* calcA = (u8*)(occB + N513);
    u8* calcB = calcA + N513;
    float* out = (float*)d_out;

    prep_w2t<<<64, 256, 0, stream>>>(W2, W2T);

    eval_all_mfma<<<2748, 512, 0, stream>>>(
        W1, b1, W2T, b2, W3, b3, bmin, bmax, q0, q1, q2, q3, q4);

    void* args[] = { &q0, &q1, &q2, &q3, &q4, &occA, &occB, &calcA, &calcB, &out };
    hipLaunchCooperativeKernel((void*)levels_coop, dim3(289), dim3(256),
                               args, 0, stream);
}

// Round 5
// 143.205 us; speedup vs baseline: 1.9403x; 1.9403x over previous
//
#include <hip/hip_runtime.h>

typedef unsigned char u8;
typedef float f32x4 __attribute__((ext_vector_type(4)));
typedef _Float16 f16x8 __attribute__((ext_vector_type(8)));

#define DIM 128
#define TM  128

__device__ __forceinline__ float fast_tanh(float x) {
    // tanh(x) = 1 - 2/(exp2(2x*log2e)+1); exact +-1 saturation via inf->0
    float e = __builtin_amdgcn_exp2f(x * 2.885390081777927f);
    return 1.0f - 2.0f * __builtin_amdgcn_rcpf(e + 1.0f);
}
__device__ __forceinline__ float fast_sigmoid(float x) {
    float e = __builtin_amdgcn_exp2f(x * -1.4426950408889634f);
    return __builtin_amdgcn_rcpf(1.0f + e);
}

// ---- prep: W2T[n][k] = fp16(W2[k][n]) ----
__global__ __launch_bounds__(256) void prep_w2t(const float* __restrict__ W2,
                                                _Float16* __restrict__ W2T) {
    int idx = blockIdx.x * 256 + threadIdx.x;   // 0..16383
    int n = idx >> 7, k = idx & 127;
    W2T[n * DIM + k] = (_Float16)W2[k * DIM + n];
}

// ---- fused MLP eval, ALL 5 resolutions, zero LDS, fp16 MFMA ----
// 8 waves/block, each wave: 16 points x 128 out-dims. Lane computes exactly
// its own MFMA A-fragment (row=lane&15, k=(lane>>4)*8..+8) -> no LDS, no barrier.
// blocks: [0,9) R33 | [9,43) R65 | [43,174) R129 | [174,691) R257 | [691,2748) R513
__global__ __launch_bounds__(512, 4) void eval_all_mfma(
    const float* __restrict__ W1, const float* __restrict__ b1,
    const _Float16* __restrict__ W2T, const float* __restrict__ b2,
    const float* __restrict__ W3, const float* __restrict__ b3,
    const float* __restrict__ bmin, const float* __restrict__ bmax,
    float* __restrict__ q0, float* __restrict__ q1, float* __restrict__ q2,
    float* __restrict__ q3, float* __restrict__ q4)
{
    const int tid = threadIdx.x;
    const int bid = blockIdx.x;
    int R, m0; float* out;
    if      (bid < 9)   { R = 33;  out = q0; m0 = bid * TM; }
    else if (bid < 43)  { R = 65;  out = q1; m0 = (bid - 9) * TM; }
    else if (bid < 174) { R = 129; out = q2; m0 = (bid - 43) * TM; }
    else if (bid < 691) { R = 257; out = q3; m0 = (bid - 174) * TM; }
    else                { R = 513; out = q4; m0 = (bid - 691) * TM; }
    const int N = R * R;

    const int w = tid >> 6, lane = tid & 63;
    const int l15 = lane & 15, lg = lane >> 4;

    // this lane's point for layer-1 (A-fragment row = l15)
    const int pi = m0 + w * 16 + l15;
    const int pg = (pi < N) ? pi : N - 1;
    const int gi = pg / R, gj = pg - gi * R;
    const float inv = 1.0f / (float)(R - 1);    // R-1 pow2 -> exact
    const float x = bmin[0] + (float)gj * inv * (bmax[0] - bmin[0]);
    const float y = bmin[1] + (float)gi * inv * (bmax[1] - bmin[1]);

    f32x4 acc[8];
    #pragma unroll
    for (int nf = 0; nf < 8; ++nf) acc[nf] = (f32x4)(0.0f);

    #pragma unroll
    for (int kf = 0; kf < 4; ++kf) {
        const int kbase = kf * 32 + lg * 8;     // this lane's k-octet
        f32x4 wxa = *(const f32x4*)&W1[kbase];
        f32x4 wxb = *(const f32x4*)&W1[kbase + 4];
        f32x4 wya = *(const f32x4*)&W1[DIM + kbase];
        f32x4 wyb = *(const f32x4*)&W1[DIM + kbase + 4];
        f32x4 b1a = *(const f32x4*)&b1[kbase];
        f32x4 b1b = *(const f32x4*)&b1[kbase + 4];
        f16x8 ah;
        #pragma unroll
        for (int qq = 0; qq < 4; ++qq)
            ah[qq] = (_Float16)fast_tanh(fmaf(x, wxa[qq], fmaf(y, wya[qq], b1a[qq])));
        #pragma unroll
        for (int qq = 0; qq < 4; ++qq)
            ah[4 + qq] = (_Float16)fast_tanh(fmaf(x, wxb[qq], fmaf(y, wyb[qq], b1b[qq])));
        #pragma unroll
        for (int nf = 0; nf < 8; ++nf) {
            int c = nf * 16 + l15;              // B col = lane&15
            f16x8 bh = *(const f16x8*)&W2T[c * DIM + kbase];
            acc[nf] = __builtin_amdgcn_mfma_f32_16x16x32_f16(ah, bh, acc[nf], 0, 0, 0);
        }
    }

    // ---- epilogue in registers ----
    // C/D: row(point) = w*16 + lg*4 + rg, col = nf*16 + l15
    float rs[4] = {0.0f, 0.0f, 0.0f, 0.0f};
    #pragma unroll
    for (int nf = 0; nf < 8; ++nf) {
        int c = nf * 16 + l15;
        float w3v = W3[c], b2v = b2[c];
        #pragma unroll
        for (int rg = 0; rg < 4; ++rg)
            rs[rg] += fast_tanh(acc[nf][rg] + b2v) * w3v;
    }
    #pragma unroll
    for (int rg = 0; rg < 4; ++rg) {
        float v = rs[rg];
        v += __shfl_xor(v, 1);
        v += __shfl_xor(v, 2);
        v += __shfl_xor(v, 4);
        v += __shfl_xor(v, 8);
        rs[rg] = v;
    }
    if (l15 == 0) {
        float b3v = b3[0];
        #pragma unroll
        for (int rg = 0; rg < 4; ++rg) {
            int po = m0 + w * 16 + lg * 4 + rg;
            if (po < N) out[po] = fast_sigmoid(rs[rg] + b3v);
        }
    }
}

// ---- per level: upsample + raw + boundary + 3 conflict iters, tiled in LDS ----
// Early-exit: if no raw boundary bits in the 40x40 region (incl. halo), skip
// phases 2-5 entirely (pure write-through) -- the 0.5-contour touches few tiles.
#define TS 32
#define HW 40   // TS + 2*4 halo
#define NTHREADS 512
__global__ __launch_bounds__(NTHREADS) void level_kernel(
    const float* __restrict__ occP, const u8* __restrict__ calcP, int Rp,
    const float* __restrict__ q, float* __restrict__ occOut,
    u8* __restrict__ calcOut, int R)
{
    __shared__ float sOcc[HW * HW], sQ[HW * HW];
    __shared__ u8 sRaw[HW * HW], sCalc[HW * HW], sCfA[HW * HW], sCfB[HW * HW];
    const int nT = (R + TS - 1) / TS;
    const int bi = blockIdx.x / nT, bj = blockIdx.x - bi * nT;
    const int fi0 = bi * TS - 4, fj0 = bj * TS - 4;
    const int tid = threadIdx.x;
    const float BAL = 0.5f;

    // phase 1: occ-interp + raw + c0 + q for the whole 40x40 region
    bool anyRaw = false;
    for (int c = tid; c < HW * HW; c += NTHREADS) {
        int li = c / HW, lj = c - li * HW;
        int fi = fi0 + li, fj = fj0 + lj;
        float occi = 0.5f, qv = 0.5f; u8 rw = 0, cal = 0;
        if (fi >= 0 && fi < R && fj >= 0 && fj < R) {
            int ip = fi >> 1, jp = fj >> 1;
            float tl = occP[ip * Rp + jp];
            int oi = fi & 1, oj = fj & 1;
            bool b;
            if (!oi && !oj) { occi = tl; b = false; }
            else if (oi && !oj) {
                float bl = occP[(ip + 1) * Rp + jp];
                occi = 0.5f * (tl + bl);
                b = (tl > BAL) != (bl > BAL);
            } else if (!oi && oj) {
                float tr = occP[ip * Rp + jp + 1];
                occi = 0.5f * (tl + tr);
                b = (tl > BAL) != (tr > BAL);
            } else {
                float bl = occP[(ip + 1) * Rp + jp];
                float tr = occP[ip * Rp + jp + 1];
                float br = occP[(ip + 1) * Rp + jp + 1];
                occi = 0.5f * (0.5f * (tl + bl) + 0.5f * (tr + br)); // exact _up2 order
                bool m0 = tl > BAL, m1 = bl > BAL, m2 = tr > BAL, m3 = br > BAL;
                b = (m0 | m1 | m2 | m3) && !(m0 & m1 & m2 & m3);
            }
            rw = b ? 1 : 0;
            if (((fi | fj) & 1) == 0) cal = calcP ? calcP[ip * Rp + jp] : 1;
            qv = q[fi * R + fj];
        }
        sOcc[c] = occi; sQ[c] = qv; sRaw[c] = rw; sCalc[c] = cal;
        sCfA[c] = 0; sCfB[c] = 0;
        anyRaw |= (rw != 0);
    }

    if (__syncthreads_or(anyRaw ? 1 : 0)) {
        // phase 2: boundary = any3x3(raw) & ~c0; seed conflicts; occ select
        bool anyCf = false;
        for (int c = tid; c < HW * HW; c += NTHREADS) {
            int li = c / HW, lj = c - li * HW;
            if (li < 1 || li >= HW - 1 || lj < 1 || lj >= HW - 1) continue;
            int fi = fi0 + li, fj = fj0 + lj;
            if (fi < 0 || fi >= R || fj < 0 || fj >= R) continue;
            bool b = false;
            #pragma unroll
            for (int di = -1; di <= 1; ++di)
                #pragma unroll
                for (int dj = -1; dj <= 1; ++dj)
                    if (sRaw[(li + di) * HW + (lj + dj)]) b = true;
            b = b && !sCalc[c];
            float oi = sOcc[c], qq = sQ[c];
            u8 cf = (b && (oi - BAL) * (qq - BAL) < 0.0f) ? 1 : 0;
            if (b) { sOcc[c] = qq; sCalc[c] = 1; }
            sCfA[c] = cf;
            anyCf |= (cf != 0);
        }
        int haveCf = __syncthreads_or(anyCf ? 1 : 0);

        // 3 conflict-propagation iterations (skip when no conflicts remain)
        for (int it = 0; it < 3 && haveCf; ++it) {
            const u8* cin = (it & 1) ? sCfB : sCfA;
            u8* cout      = (it & 1) ? sCfA : sCfB;
            int lo = 2 + it, hi = HW - 2 - it;
            bool anyNc = false;
            for (int c = tid; c < HW * HW; c += NTHREADS) {
                int li = c / HW, lj = c - li * HW;
                if (li < lo || li >= hi || lj < lo || lj >= hi) continue;
                int fi = fi0 + li, fj = fj0 + lj;
                if (fi < 0 || fi >= R || fj < 0 || fj >= R) continue;
                bool any = false;
                #pragma unroll
                for (int di = -1; di <= 1; ++di)
                    #pragma unroll
                    for (int dj = -1; dj <= 1; ++dj)
                        if (cin[(li + di) * HW + (lj + dj)]) any = true;
                bool cand = any && !sCalc[c];
                float oc = sOcc[c], qq = sQ[c];
                u8 nc = (cand && (oc - BAL) * (qq - BAL) < 0.0f) ? 1 : 0;
                if (cand) { sOcc[c] = qq; sCalc[c] = 1; }
                cout[c] = nc;
                anyNc |= (nc != 0);
            }
            haveCf = __syncthreads_or(anyNc ? 1 : 0);
        }
    }

    // write core 32x32 (synchronized by the last __syncthreads_or on all paths)
    for (int c = tid; c < HW * HW; c += NTHREADS) {
        int li = c / HW, lj = c - li * HW;
        if (li < 4 || li >= HW - 4 || lj < 4 || lj >= HW - 4) continue;
        int fi = fi0 + li, fj = fj0 + lj;
        if (fi < 0 || fi >= R || fj < 0 || fj >= R) continue;
        occOut[fi * R + fj] = sOcc[c];
        calcOut[fi * R + fj] = sCalc[c];
    }
}

extern "C" void kernel_launch(void* const* d_in, const int* in_sizes, int n_in,
                              void* d_out, int out_size, void* d_ws, size_t ws_size,
                              hipStream_t stream) {
    const float* W1   = (const float*)d_in[0];
    const float* b1   = (const float*)d_in[1];
    const float* W2   = (const float*)d_in[2];
    const float* b2   = (const float*)d_in[3];
    const float* W3   = (const float*)d_in[4];
    const float* b3   = (const float*)d_in[5];
    const float* bmin = (const float*)d_in[6];
    const float* bmax = (const float*)d_in[7];

    const int N33 = 33 * 33, N65 = 65 * 65, N129 = 129 * 129,
              N257 = 257 * 257, N513 = 513 * 513;

    _Float16* W2T = (_Float16*)d_ws;                   // 32 KB, 16B-aligned
    float* q0 = (float*)((char*)d_ws + 32768);
    float* q1 = q0 + N33;
    float* q2 = q1 + N65;
    float* q3 = q2 + N129;
    float* q4 = q3 + N257;
    float* occA = q4 + N513;
    float* occB = occA + N513;
    u8* calcA = (u8*)(occB + N513);
    u8* calcB = calcA + N513;
    float* out = (float*)d_out;

    prep_w2t<<<64, 256, 0, stream>>>(W2, W2T);

    eval_all_mfma<<<2748, 512, 0, stream>>>(
        W1, b1, W2T, b2, W3, b3, bmin, bmax, q0, q1, q2, q3, q4);

    level_kernel<<<9,   NTHREADS, 0, stream>>>(q0,   (const u8*)nullptr, 33,  q1, occA, calcB, 65);
    level_kernel<<<25,  NTHREADS, 0, stream>>>(occA, calcB,              65,  q2, occB, calcA, 129);
    level_kernel<<<81,  NTHREADS, 0, stream>>>(occB, calcA,              129, q3, occA, calcB, 257);
    level_kernel<<<289, NTHREADS, 0, stream>>>(occA, calcB,              257, q4, out,  calcA, 513);
}

// Round 6
// 74.796 us; speedup vs baseline: 3.7149x; 1.9146x over previous
//
#include <hip/hip_runtime.h>

typedef unsigned char u8;
typedef float f32x4 __attribute__((ext_vector_type(4)));
typedef _Float16 f16x8 __attribute__((ext_vector_type(8)));

#define DIM 128
#define TM  256   // points per block (8 waves x 32 points)

__device__ __forceinline__ float fast_tanh(float x) {
    // tanh(x) = 1 - 2/(exp2(2x*log2e)+1); exact +-1 saturation via inf->0
    float e = __builtin_amdgcn_exp2f(x * 2.885390081777927f);
    return 1.0f - 2.0f * __builtin_amdgcn_rcpf(e + 1.0f);
}
__device__ __forceinline__ float fast_sigmoid(float x) {
    float e = __builtin_amdgcn_exp2f(x * -1.4426950408889634f);
    return __builtin_amdgcn_rcpf(1.0f + e);
}

// ---- fused MLP eval, ALL 5 resolutions, fp16 MFMA, W2T staged in LDS ----
// 8 waves/block, each wave: 32 points x 128 out-dims (mf=2 A-fragments).
// Lane computes its own A-fragments (row=lane&15, k=(lane>>4)*8..+8) -> layer-1
// output never leaves registers. B (W2T fp16) is transposed into LDS once per
// block (XOR-swizzled 16B chunks -> conflict-free ds_read_b128 in the k-loop).
// blocks: [0,5) R33 | [5,22) R65 | [22,88) R129 | [88,347) R257 | [347,1376) R513
__global__ __launch_bounds__(512, 4) void eval_all_mfma(
    const float* __restrict__ W1, const float* __restrict__ b1,
    const float* __restrict__ W2, const float* __restrict__ b2,
    const float* __restrict__ W3, const float* __restrict__ b3,
    const float* __restrict__ bmin, const float* __restrict__ bmax,
    float* __restrict__ q0, float* __restrict__ q1, float* __restrict__ q2,
    float* __restrict__ q3, float* __restrict__ q4)
{
    __shared__ __align__(16) _Float16 sW2T[DIM * DIM];   // 32 KB

    const int tid = threadIdx.x;
    const int bid = blockIdx.x;
    int R, m0; float* out;
    if      (bid < 5)   { R = 33;  out = q0; m0 = bid * TM; }
    else if (bid < 22)  { R = 65;  out = q1; m0 = (bid - 5) * TM; }
    else if (bid < 88)  { R = 129; out = q2; m0 = (bid - 22) * TM; }
    else if (bid < 347) { R = 257; out = q3; m0 = (bid - 88) * TM; }
    else                { R = 513; out = q4; m0 = (bid - 347) * TM; }
    const int N = R * R;

    // ---- stage W2T into LDS: chunk(n,ko) = fp16(W2[ko*8+q][n]), swizzled ----
    #pragma unroll
    for (int s = 0; s < 4; ++s) {
        int chunk = s * 512 + tid;       // 0..2047
        int n  = chunk & 127;
        int ko = chunk >> 7;             // k-octet 0..15
        f16x8 v;
        #pragma unroll
        for (int qq = 0; qq < 8; ++qq)
            v[qq] = (_Float16)W2[(ko * 8 + qq) * DIM + n];   // coalesced over n
        int slot = ko ^ (n & 15);
        *(f16x8*)&sW2T[n * DIM + slot * 8] = v;
    }

    const int w = tid >> 6, lane = tid & 63;
    const int l15 = lane & 15, lg = lane >> 4;

    // two points per lane (A rows l15 of the two 16-row fragments)
    const float inv = 1.0f / (float)(R - 1);    // R-1 pow2 -> exact
    const float bx0 = bmin[0], by0 = bmin[1];
    const float sx = bmax[0] - bx0, sy = bmax[1] - by0;
    float xs[2], ys[2];
    #pragma unroll
    for (int mf = 0; mf < 2; ++mf) {
        int pi = m0 + w * 32 + mf * 16 + l15;
        int pg = (pi < N) ? pi : N - 1;
        int gi = pg / R, gj = pg - gi * R;
        xs[mf] = bx0 + (float)gj * inv * sx;
        ys[mf] = by0 + (float)gi * inv * sy;
    }

    f32x4 acc[2][8];
    #pragma unroll
    for (int mf = 0; mf < 2; ++mf)
        #pragma unroll
        for (int nf = 0; nf < 8; ++nf) acc[mf][nf] = (f32x4)(0.0f);

    __syncthreads();

    #pragma unroll
    for (int kf = 0; kf < 4; ++kf) {
        const int kbase = kf * 32 + lg * 8;     // this lane's k-octet
        // issue the 8 B-fragment LDS reads up front (hidden under tanh chain)
        f16x8 bh[8];
        #pragma unroll
        for (int nf = 0; nf < 8; ++nf) {
            int c = nf * 16 + l15;
            int slot = (kf * 4 + lg) ^ l15;     // matches write swizzle (c&15==l15)
            bh[nf] = *(const f16x8*)&sW2T[c * DIM + slot * 8];
        }
        // layer-1: 16 independent tanh per lane
        f32x4 wxa = *(const f32x4*)&W1[kbase];
        f32x4 wxb = *(const f32x4*)&W1[kbase + 4];
        f32x4 wya = *(const f32x4*)&W1[DIM + kbase];
        f32x4 wyb = *(const f32x4*)&W1[DIM + kbase + 4];
        f32x4 b1a = *(const f32x4*)&b1[kbase];
        f32x4 b1b = *(const f32x4*)&b1[kbase + 4];
        f16x8 ah[2];
        #pragma unroll
        for (int mf = 0; mf < 2; ++mf) {
            float x = xs[mf], y = ys[mf];
            #pragma unroll
            for (int qq = 0; qq < 4; ++qq)
                ah[mf][qq] = (_Float16)fast_tanh(fmaf(x, wxa[qq], fmaf(y, wya[qq], b1a[qq])));
            #pragma unroll
            for (int qq = 0; qq < 4; ++qq)
                ah[mf][4 + qq] = (_Float16)fast_tanh(fmaf(x, wxb[qq], fmaf(y, wyb[qq], b1b[qq])));
        }
        #pragma unroll
        for (int nf = 0; nf < 8; ++nf)
            #pragma unroll
            for (int mf = 0; mf < 2; ++mf)
                acc[mf][nf] = __builtin_amdgcn_mfma_f32_16x16x32_f16(ah[mf], bh[nf], acc[mf][nf], 0, 0, 0);
    }

    // ---- epilogue in registers ----
    // C/D: row(point) = w*32 + mf*16 + lg*4 + rg, col = nf*16 + l15
    float rs[2][4] = {{0,0,0,0},{0,0,0,0}};
    #pragma unroll
    for (int nf = 0; nf < 8; ++nf) {
        int c = nf * 16 + l15;
        float w3v = W3[c], b2v = b2[c];
        #pragma unroll
        for (int mf = 0; mf < 2; ++mf)
            #pragma unroll
            for (int rg = 0; rg < 4; ++rg)
                rs[mf][rg] += fast_tanh(acc[mf][nf][rg] + b2v) * w3v;
    }
    #pragma unroll
    for (int mf = 0; mf < 2; ++mf)
        #pragma unroll
        for (int rg = 0; rg < 4; ++rg) {
            float v = rs[mf][rg];
            v += __shfl_xor(v, 1);
            v += __shfl_xor(v, 2);
            v += __shfl_xor(v, 4);
            v += __shfl_xor(v, 8);
            rs[mf][rg] = v;
        }
    if (l15 == 0) {
        float b3v = b3[0];
        #pragma unroll
        for (int mf = 0; mf < 2; ++mf)
            #pragma unroll
            for (int rg = 0; rg < 4; ++rg) {
                int po = m0 + w * 32 + mf * 16 + lg * 4 + rg;
                if (po < N) out[po] = fast_sigmoid(rs[mf][rg] + b3v);
            }
    }
}

// ---- per level: upsample + raw + boundary + 3 conflict iters, tiled in LDS ----
// Early-exit: if no raw boundary bits in the 40x40 region (incl. halo), skip
// phases 2-5 entirely (pure write-through) -- the 0.5-contour touches few tiles.
#define TS 32
#define HW 40   // TS + 2*4 halo
#define NTHREADS 512
__global__ __launch_bounds__(NTHREADS) void level_kernel(
    const float* __restrict__ occP, const u8* __restrict__ calcP, int Rp,
    const float* __restrict__ q, float* __restrict__ occOut,
    u8* __restrict__ calcOut, int R)
{
    __shared__ float sOcc[HW * HW], sQ[HW * HW];
    __shared__ u8 sRaw[HW * HW], sCalc[HW * HW], sCfA[HW * HW], sCfB[HW * HW];
    const int nT = (R + TS - 1) / TS;
    const int bi = blockIdx.x / nT, bj = blockIdx.x - bi * nT;
    const int fi0 = bi * TS - 4, fj0 = bj * TS - 4;
    const int tid = threadIdx.x;
    const float BAL = 0.5f;

    // phase 1: occ-interp + raw + c0 + q for the whole 40x40 region
    bool anyRaw = false;
    for (int c = tid; c < HW * HW; c += NTHREADS) {
        int li = c / HW, lj = c - li * HW;
        int fi = fi0 + li, fj = fj0 + lj;
        float occi = 0.5f, qv = 0.5f; u8 rw = 0, cal = 0;
        if (fi >= 0 && fi < R && fj >= 0 && fj < R) {
            int ip = fi >> 1, jp = fj >> 1;
            float tl = occP[ip * Rp + jp];
            int oi = fi & 1, oj = fj & 1;
            bool b;
            if (!oi && !oj) { occi = tl; b = false; }
            else if (oi && !oj) {
                float bl = occP[(ip + 1) * Rp + jp];
                occi = 0.5f * (tl + bl);
                b = (tl > BAL) != (bl > BAL);
            } else if (!oi && oj) {
                float tr = occP[ip * Rp + jp + 1];
                occi = 0.5f * (tl + tr);
                b = (tl > BAL) != (tr > BAL);
            } else {
                float bl = occP[(ip + 1) * Rp + jp];
                float tr = occP[ip * Rp + jp + 1];
                float br = occP[(ip + 1) * Rp + jp + 1];
                occi = 0.5f * (0.5f * (tl + bl) + 0.5f * (tr + br)); // exact _up2 order
                bool m0 = tl > BAL, m1 = bl > BAL, m2 = tr > BAL, m3 = br > BAL;
                b = (m0 | m1 | m2 | m3) && !(m0 & m1 & m2 & m3);
            }
            rw = b ? 1 : 0;
            if (((fi | fj) & 1) == 0) cal = calcP ? calcP[ip * Rp + jp] : 1;
            qv = q[fi * R + fj];
        }
        sOcc[c] = occi; sQ[c] = qv; sRaw[c] = rw; sCalc[c] = cal;
        sCfA[c] = 0; sCfB[c] = 0;
        anyRaw |= (rw != 0);
    }

    if (__syncthreads_or(anyRaw ? 1 : 0)) {
        // phase 2: boundary = any3x3(raw) & ~c0; seed conflicts; occ select
        bool anyCf = false;
        for (int c = tid; c < HW * HW; c += NTHREADS) {
            int li = c / HW, lj = c - li * HW;
            if (li < 1 || li >= HW - 1 || lj < 1 || lj >= HW - 1) continue;
            int fi = fi0 + li, fj = fj0 + lj;
            if (fi < 0 || fi >= R || fj < 0 || fj >= R) continue;
            bool b = false;
            #pragma unroll
            for (int di = -1; di <= 1; ++di)
                #pragma unroll
                for (int dj = -1; dj <= 1; ++dj)
                    if (sRaw[(li + di) * HW + (lj + dj)]) b = true;
            b = b && !sCalc[c];
            float oi = sOcc[c], qq = sQ[c];
            u8 cf = (b && (oi - BAL) * (qq - BAL) < 0.0f) ? 1 : 0;
            if (b) { sOcc[c] = qq; sCalc[c] = 1; }
            sCfA[c] = cf;
            anyCf |= (cf != 0);
        }
        int haveCf = __syncthreads_or(anyCf ? 1 : 0);

        // 3 conflict-propagation iterations (skip when no conflicts remain)
        for (int it = 0; it < 3 && haveCf; ++it) {
            const u8* cin = (it & 1) ? sCfB : sCfA;
            u8* cout      = (it & 1) ? sCfA : sCfB;
            int lo = 2 + it, hi = HW - 2 - it;
            bool anyNc = false;
            for (int c = tid; c < HW * HW; c += NTHREADS) {
                int li = c / HW, lj = c - li * HW;
                if (li < lo || li >= hi || lj < lo || lj >= hi) continue;
                int fi = fi0 + li, fj = fj0 + lj;
                if (fi < 0 || fi >= R || fj < 0 || fj >= R) continue;
                bool any = false;
                #pragma unroll
                for (int di = -1; di <= 1; ++di)
                    #pragma unroll
                    for (int dj = -1; dj <= 1; ++dj)
                        if (cin[(li + di) * HW + (lj + dj)]) any = true;
                bool cand = any && !sCalc[c];
                float oc = sOcc[c], qq = sQ[c];
                u8 nc = (cand && (oc - BAL) * (qq - BAL) < 0.0f) ? 1 : 0;
                if (cand) { sOcc[c] = qq; sCalc[c] = 1; }
                cout[c] = nc;
                anyNc |= (nc != 0);
            }
            haveCf = __syncthreads_or(anyNc ? 1 : 0);
        }
    }

    // write core 32x32 (synchronized by the last __syncthreads_or on all paths)
    for (int c = tid; c < HW * HW; c += NTHREADS) {
        int li = c / HW, lj = c - li * HW;
        if (li < 4 || li >= HW - 4 || lj < 4 || lj >= HW - 4) continue;
        int fi = fi0 + li, fj = fj0 + lj;
        if (fi < 0 || fi >= R || fj < 0 || fj >= R) continue;
        occOut[fi * R + fj] = sOcc[c];
        calcOut[fi * R + fj] = sCalc[c];
    }
}

extern "C" void kernel_launch(void* const* d_in, const int* in_sizes, int n_in,
                              void* d_out, int out_size, void* d_ws, size_t ws_size,
                              hipStream_t stream) {
    const float* W1   = (const float*)d_in[0];
    const float* b1   = (const float*)d_in[1];
    const float* W2   = (const float*)d_in[2];
    const float* b2   = (const float*)d_in[3];
    const float* W3   = (const float*)d_in[4];
    const float* b3   = (const float*)d_in[5];
    const float* bmin = (const float*)d_in[6];
    const float* bmax = (const float*)d_in[7];

    const int N33 = 33 * 33, N65 = 65 * 65, N129 = 129 * 129,
              N257 = 257 * 257, N513 = 513 * 513;

    float* q0 = (float*)d_ws;
    float* q1 = q0 + N33;
    float* q2 = q1 + N65;
    float* q3 = q2 + N129;
    float* q4 = q3 + N257;
    float* occA = q4 + N513;
    float* occB = occA + N513;
    u8* calcA = (u8*)(occB + N513);
    u8* calcB = calcA + N513;
    float* out = (float*)d_out;

    eval_all_mfma<<<1376, 512, 0, stream>>>(
        W1, b1, W2, b2, W3, b3, bmin, bmax, q0, q1, q2, q3, q4);

    level_kernel<<<9,   NTHREADS, 0, stream>>>(q0,   (const u8*)nullptr, 33,  q1, occA, calcB, 65);
    level_kernel<<<25,  NTHREADS, 0, stream>>>(occA, calcB,              65,  q2, occB, calcA, 129);
    level_kernel<<<81,  NTHREADS, 0, stream>>>(occB, calcA,              129, q3, occA, calcB, 257);
    level_kernel<<<289, NTHREADS, 0, stream>>>(occA, calcB,              257, q4, out,  calcA, 513);
}